// Round 6
// baseline (439.907 us; speedup 1.0000x reference)
//
#include <hip/hip_runtime.h>

constexpr int B      = 4;
constexpr int T      = 4096;
constexpr int C      = 64;                 // input dim
constexpr int H      = 64;                 // head dim
constexpr int TILE   = 32;                 // query rows per block
constexpr int HALO   = 2;                  // window radius
constexpr int HR     = TILE + 2 * HALO;    // 36 halo rows
constexpr int LS     = 68;                 // LDS row stride (floats): float4-aligned, rotates banks by 4/row
constexpr int NT     = 256;
constexpr int NTILES = T / TILE;           // 128

typedef float f32x4 __attribute__((ext_vector_type(4)));

// Single fused kernel, r1 store structure (empirically fastest end-to-end:
// r1=283 vs r2..r5=400-449 bench):
//   - zero-fill of this block's 32 attn rows issued at kernel START,
//     drained by the first __syncthreads (vmcnt(0)) while all 512 blocks
//     stream concurrently -> clean 1x write traffic, no RMW signature.
//   - band probs written later as scalar dwords into our own zeroed rows.
// Compute is r2-style: W row per lane in registers, all 256 threads active.
__global__ __launch_bounds__(NT, 2)
void sparse_attn_fused(const float* __restrict__ x,
                       const float* __restrict__ Wq,
                       const float* __restrict__ Wk,
                       const float* __restrict__ Wv,
                       float* __restrict__ out)
{
    __shared__ float sX[HR][LS];       // x halo rows
    __shared__ float sQ[TILE][LS];
    __shared__ float sK[HR][LS];
    __shared__ float sV[HR][LS];
    __shared__ float sS[TILE][8];      // scores, then probs (5 used per row)

    const int tid  = threadIdx.x;
    const int b    = blockIdx.x / NTILES;
    const int tile = blockIdx.x % NTILES;
    const int row0 = tile * TILE;
    const float* xb = x + (size_t)b * T * C;
    const size_t attnBase = (size_t)B * T * H;

    // ---- phase 0a: stage x halo rows into LDS (zero-padded at batch edges) ----
    for (int s = tid; s < HR * (C / 4); s += NT) {
        const int lr = s >> 4;
        const int c4 = (s & 15) << 2;
        const int gr = row0 + lr - HALO;
        float4 v = make_float4(0.f, 0.f, 0.f, 0.f);
        if (gr >= 0 && gr < T) v = *(const float4*)(xb + (size_t)gr * C + c4);
        *(float4*)&sX[lr][c4] = v;
    }

    // ---- phase 0b: issue zero-fill of this block's attn rows (512 KB) ----
    // Drained by the barrier below; fill+drain is the roofline term (~42 us
    // chip-wide at 6.3 TB/s across 512 concurrent blocks).
    {
        f32x4* dst = (f32x4*)(out + attnBase + ((size_t)b * T + row0) * T);
        const f32x4 z = (f32x4)0.f;
        for (int s = tid; s < TILE * (T / 4); s += NT) dst[s] = z;
    }

    const int h = tid & 63;      // head-dim column this lane owns
    const int w = tid >> 6;      // wave id 0..3

    // ---- phase 0c: Wq row for this lane into registers (16 KB, L2-resident) ----
    float4 wr[16];
#pragma unroll
    for (int c4 = 0; c4 < 16; ++c4) wr[c4] = *(const float4*)(Wq + h * C + c4 * 4);

    __syncthreads();   // drains fill stores + sX; fill of OUR rows now visible

    // ---- phase 1: Q = X[tile] @ Wq^T : wave w computes rows w*8..w*8+7 ----
#pragma unroll
    for (int ii = 0; ii < 8; ++ii) {
        const int i = w * 8 + ii;
        float acc = 0.f;
#pragma unroll
        for (int c4 = 0; c4 < 16; ++c4) {
            const float4 xv = *(const float4*)&sX[i + HALO][c4 * 4];
            acc = fmaf(xv.x, wr[c4].x, acc);
            acc = fmaf(xv.y, wr[c4].y, acc);
            acc = fmaf(xv.z, wr[c4].z, acc);
            acc = fmaf(xv.w, wr[c4].w, acc);
        }
        sQ[i][h] = acc;
    }

    // K = X[halo] @ Wk^T : wave w computes rows w*9..w*9+8
#pragma unroll
    for (int c4 = 0; c4 < 16; ++c4) wr[c4] = *(const float4*)(Wk + h * C + c4 * 4);
#pragma unroll
    for (int ii = 0; ii < 9; ++ii) {
        const int l = w * 9 + ii;
        float acc = 0.f;
#pragma unroll
        for (int c4 = 0; c4 < 16; ++c4) {
            const float4 xv = *(const float4*)&sX[l][c4 * 4];
            acc = fmaf(xv.x, wr[c4].x, acc);
            acc = fmaf(xv.y, wr[c4].y, acc);
            acc = fmaf(xv.z, wr[c4].z, acc);
            acc = fmaf(xv.w, wr[c4].w, acc);
        }
        sK[l][h] = acc;
    }

    // V = X[halo] @ Wv^T
#pragma unroll
    for (int c4 = 0; c4 < 16; ++c4) wr[c4] = *(const float4*)(Wv + h * C + c4 * 4);
#pragma unroll
    for (int ii = 0; ii < 9; ++ii) {
        const int l = w * 9 + ii;
        float acc = 0.f;
#pragma unroll
        for (int c4 = 0; c4 < 16; ++c4) {
            const float4 xv = *(const float4*)&sX[l][c4 * 4];
            acc = fmaf(xv.x, wr[c4].x, acc);
            acc = fmaf(xv.y, wr[c4].y, acc);
            acc = fmaf(xv.z, wr[c4].z, acc);
            acc = fmaf(xv.w, wr[c4].w, acc);
        }
        sV[l][h] = acc;
    }

    __syncthreads();

    // ---- phase 2: scores, 32 rows x 5 offsets on 160 threads ----
    if (tid < TILE * 5) {
        const int i  = tid / 5;
        const int dj = tid % 5;
        const int jg = row0 + i - HALO + dj;
        float sc = -__builtin_inff();
        if (jg >= 0 && jg < T) {
            float acc = 0.f;
#pragma unroll
            for (int c4 = 0; c4 < C; c4 += 4) {
                const float4 q = *(const float4*)&sQ[i][c4];
                const float4 k = *(const float4*)&sK[i + dj][c4];
                acc = fmaf(q.x, k.x, acc);
                acc = fmaf(q.y, k.y, acc);
                acc = fmaf(q.z, k.z, acc);
                acc = fmaf(q.w, k.w, acc);
            }
            // scale = C^-0.5 = 0.125 ; +1 bias inside band for j > i (dj > 2), per triu(ones,1)
            sc = acc * 0.125f + (dj > 2 ? 1.0f : 0.0f);
        }
        sS[i][dj] = sc;
    }
    __syncthreads();

    // ---- phase 3: softmax per row; scalar dword band stores into OUR zeroed rows ----
    if (tid < TILE) {
        const int i  = tid;
        const int ig = row0 + i;
        float sc[5];
        float m = -__builtin_inff();
#pragma unroll
        for (int d = 0; d < 5; ++d) { sc[d] = sS[i][d]; m = fmaxf(m, sc[d]); }
        float p[5];
        float sum = 0.f;
#pragma unroll
        for (int d = 0; d < 5; ++d) { p[d] = expf(sc[d] - m); sum += p[d]; }
        const float inv = 1.f / sum;
        float* rowp = out + attnBase + ((size_t)b * T + ig) * T;
#pragma unroll
        for (int d = 0; d < 5; ++d) {
            const float pv = p[d] * inv;             // exp(-inf)=0 -> prob 0 for invalid j
            sS[i][d] = pv;
            const int j = ig - HALO + d;
            if (j >= 0 && j < T) rowp[j] = pv;       // row zero-filled by THIS block, drained at barrier 1
        }
    }
    __syncthreads();

    // ---- phase 4: op = P @ V : 512 float4 outputs, coalesced ----
    for (int s = tid; s < TILE * (H / 4); s += NT) {
        const int r  = s >> 4;
        const int hq = (s & 15) << 2;
        float4 acc = make_float4(0.f, 0.f, 0.f, 0.f);
#pragma unroll
        for (int d = 0; d < 5; ++d) {
            const float pv = sS[r][d];
            const float4 vv = *(const float4*)&sV[r + d][hq];
            acc.x = fmaf(pv, vv.x, acc.x);
            acc.y = fmaf(pv, vv.y, acc.y);
            acc.z = fmaf(pv, vv.z, acc.z);
            acc.w = fmaf(pv, vv.w, acc.w);
        }
        *(float4*)(out + ((size_t)b * T + row0 + r) * H + hq) = acc;
    }
}

extern "C" void kernel_launch(void* const* d_in, const int* in_sizes, int n_in,
                              void* d_out, int out_size, void* d_ws, size_t ws_size,
                              hipStream_t stream) {
    (void)in_sizes; (void)n_in; (void)d_ws; (void)ws_size; (void)out_size;
    const float* x  = (const float*)d_in[0];
    const float* Wq = (const float*)d_in[1];
    const float* Wk = (const float*)d_in[2];
    const float* Wv = (const float*)d_in[3];
    float* out = (float*)d_out;
    sparse_attn_fused<<<dim3(B * NTILES), dim3(NT), 0, stream>>>(x, Wq, Wk, Wv, out);
}